// Round 10
// baseline (2061.440 us; speedup 1.0000x reference)
//
#include <hip/hip_runtime.h>
#include <hip/hip_bf16.h>

// ---------- types ----------
typedef __attribute__((ext_vector_type(8))) short short8;   // 8 bf16 = 4 VGPRs (MFMA A/B frag)
typedef __attribute__((ext_vector_type(4))) short short4_t; // 4 bf16
typedef __attribute__((ext_vector_type(4))) float f32x4;    // MFMA C/D frag

__device__ __forceinline__ short f2bf(float x) {
  unsigned int u = __builtin_bit_cast(unsigned int, x);
  unsigned int r = (u + 0x7fffu + ((u >> 16) & 1u)) >> 16;
  return (short)r;
}
__device__ __forceinline__ float bf2f(unsigned short u) {
  unsigned int i = ((unsigned int)u) << 16;
  return __builtin_bit_cast(float, i);
}

// packed f32x2 -> bf16x2 as an int (hardware cvt if available; safe fallback)
__device__ __forceinline__ int pkcvt(float a, float b) {
#if __has_builtin(__builtin_amdgcn_cvt_pk_bf16_f32)
  typedef __attribute__((ext_vector_type(2))) __bf16 bf16x2_t;
  bf16x2_t r = __builtin_amdgcn_cvt_pk_bf16_f32(a, b);
  return __builtin_bit_cast(int, r);
#else
  unsigned int lo = (unsigned short)f2bf(a);
  unsigned int hi = (unsigned short)f2bf(b);
  return (int)(lo | (hi << 16));
#endif
}

// lgkmcnt-only barrier (no vmcnt drain — global prefetches stay in flight)
#define LDS_BARRIER() asm volatile("s_waitcnt lgkmcnt(0)\n\ts_barrier" ::: "memory")

// ---------- kernel W: convert Wh and Wi fp32 -> bf16 ----------
__global__ __launch_bounds__(256) void kcvt(const float* __restrict__ Wh,
                                            const float* __restrict__ Wi,
                                            short* __restrict__ Whb,
                                            short* __restrict__ Wib) {
  int i = blockIdx.x * 256 + threadIdx.x;   // 0..98303 float4 groups
  const float4* src; short4_t* dst; int j;
  if (i < 65536) { src = (const float4*)Wh; dst = (short4_t*)Whb; j = i; }
  else           { src = (const float4*)Wi; dst = (short4_t*)Wib; j = i - 65536; }
  float4 v = src[j];
  short4_t o;
  o[0] = f2bf(v.x); o[1] = f2bf(v.y); o[2] = f2bf(v.z); o[3] = f2bf(v.w);
  dst[j] = o;
}

// ---------- kernel A (MFMA): xp[s][b][h] = sum_e emb[ids[b][s]][e]*Wi[h][e] + bi[h] + bh[h] ----------
// One block per s. 8 waves; wave w owns h range [64w, 64w+64) (4 N-tiles).
// A = emb rows (bf16, staged in LDS), B = Wib rows (bf16, straight from L2).
__global__ __launch_bounds__(512, 2) void kxproj(const int* __restrict__ ids,    // [B=64][S=512]
                                                 const float* __restrict__ emb,  // [V][256] fp32
                                                 const short* __restrict__ Wib,  // [512][256] bf16
                                                 const float* __restrict__ bi,   // [512]
                                                 const float* __restrict__ bh,   // [512]
                                                 short* __restrict__ xp) {       // [S][64][512] bf16
  const int s = blockIdx.x;
  __shared__ short E[64 * 264];   // [b][e] bf16, row stride 264 shorts (528 B)
  __shared__ float bias[512];
  __shared__ int ids_s[64];
  const int tid = threadIdx.x;    // 0..511
  const int w = tid >> 6, l = tid & 63, n = l & 15, q = l >> 4;

  if (tid < 64) ids_s[tid] = ids[tid * 512 + s];
  if (tid < 256) {
    bias[tid]       = bi[tid]       + bh[tid];
    bias[tid + 256] = bi[tid + 256] + bh[tid + 256];
  }
  __syncthreads();

  // stage emb rows -> bf16 LDS: thread t handles row t>>3, 32-e chunk (t&7)
  {
    const int row = tid >> 3, part = tid & 7;
    const float* src = &emb[(size_t)ids_s[row] * 256 + part * 32];
    short* dst = &E[row * 264 + part * 32];
    #pragma unroll
    for (int j = 0; j < 8; ++j) {
      float4 v = ((const float4*)src)[j];
      int2 pk;
      pk.x = pkcvt(v.x, v.y);
      pk.y = pkcvt(v.z, v.w);
      *(int2*)&dst[j * 4] = pk;
    }
  }
  __syncthreads();

  // GEMM: M=64 (batches), N=64 per wave, K=256
  f32x4 acc[4][4];   // [mt][nt]
  #pragma unroll
  for (int mt = 0; mt < 4; ++mt)
    #pragma unroll
    for (int nt = 0; nt < 4; ++nt) acc[mt][nt] = (f32x4){0.f, 0.f, 0.f, 0.f};

  const short* bbase = &Wib[(size_t)(w * 64 + n) * 256 + q * 8];
  #pragma unroll
  for (int kt = 0; kt < 8; ++kt) {
    short8 afrag[4];
    #pragma unroll
    for (int mt = 0; mt < 4; ++mt)
      afrag[mt] = *(const short8*)&E[(mt * 16 + n) * 264 + kt * 32 + q * 8];
    #pragma unroll
    for (int nt = 0; nt < 4; ++nt) {
      short8 bfrag = *(const short8*)&bbase[nt * 16 * 256 + kt * 32];
      #pragma unroll
      for (int mt = 0; mt < 4; ++mt)
        acc[mt][nt] = __builtin_amdgcn_mfma_f32_16x16x32_bf16(afrag[mt], bfrag, acc[mt][nt], 0, 0, 0);
    }
  }

  // epilogue: + bias, cvt bf16, store
  #pragma unroll
  for (int nt = 0; nt < 4; ++nt) {
    float bv = bias[w * 64 + nt * 16 + n];
    #pragma unroll
    for (int mt = 0; mt < 4; ++mt) {
      #pragma unroll
      for (int i = 0; i < 4; ++i) {
        short sv = f2bf(acc[mt][nt][i] + bv);
        xp[((size_t)s * 64 + mt * 16 + q * 4 + i) * 512 + w * 64 + nt * 16 + n] = sv;
      }
    }
  }
}

// ---------- kernel B: the recurrence. 4 WGs x 16 batches, 8 waves (2/SIMD). ----------
// ALL FOUR A-tiles register-resident (256 reg-frags/wave — uses the gfx950
// unified VGPR/AGPR file; MFMA reads A directly from AGPRs, no LDS A reads).
// h state swizzled fragment-major and double-buffered -> per-kt B-frag read is
// one linear conflict-free ds_read_b128, ONE lgkm-barrier per step.
// DS traffic/step/wave: 16 b128 reads + 4 b64 writes (was 31 + 4).
__global__ __launch_bounds__(512, 2) void krnn(const short* __restrict__ Whb, // [512][512] bf16
                                               const short* __restrict__ xp,  // [S][64][512] bf16
                                               float* __restrict__ d_out) {
  __shared__ short h_lds[2][16 * 512];      // 2 x 16,384 B (swizzled); total LDS 32 KiB
  const int tid = threadIdx.x;
  const int w   = tid >> 6;       // wave 0..7
  const int l   = tid & 63;
  const int n   = l & 15;         // MFMA col / batch-in-group / A-row-in-tile
  const int q   = l >> 4;         // quad 0..3
  const int g   = blockIdx.x;     // batch group 0..3
  const int m0  = w * 64;

  // zero h buf 0 (read at s=0)
  for (int i = tid; i < 16 * 512 / 2; i += 512) ((int*)h_lds[0])[i] = 0;

  // register A-frags, ALL tiles 0..3: A[m = n][k = q*8+j]
  short8 areg[4][16];
  #pragma unroll
  for (int t = 0; t < 4; ++t) {
    const short* base = &Whb[(m0 + t * 16 + n) * 512 + q * 8];
    #pragma unroll
    for (int kt = 0; kt < 16; ++kt) areg[t][kt] = *(const short8*)&base[kt * 32];
  }
  __syncthreads();

  // x for current step: 4 short4 chunks (t tiles, q offset)
  const short* xrow = &xp[(size_t)(g * 16 + n) * 512 + m0];
  short4_t xv[4];
  #pragma unroll
  for (int t = 0; t < 4; ++t) xv[t] = *(const short4_t*)&xrow[t * 16 + q * 4];

  for (int s = 0; s < 512; ++s) {
    const short* rb = h_lds[s & 1];
    short*       wb = h_lds[1 - (s & 1)];

    f32x4 acc[4];
    #pragma unroll
    for (int t = 0; t < 4; ++t) acc[t] = (f32x4){0.f, 0.f, 0.f, 0.f};

    #pragma unroll
    for (int kt = 0; kt < 16; ++kt) {
      short8 bfrag = *(const short8*)&rb[kt * 512 + l * 8];     // linear, conflict-free
      acc[0] = __builtin_amdgcn_mfma_f32_16x16x32_bf16(areg[0][kt], bfrag, acc[0], 0, 0, 0);
      acc[1] = __builtin_amdgcn_mfma_f32_16x16x32_bf16(areg[1][kt], bfrag, acc[1], 0, 0, 0);
      acc[2] = __builtin_amdgcn_mfma_f32_16x16x32_bf16(areg[2][kt], bfrag, acc[2], 0, 0, 0);
      acc[3] = __builtin_amdgcn_mfma_f32_16x16x32_bf16(areg[3][kt], bfrag, acc[3], 0, 0, 0);
    }
    // no barrier here: reads hit rb, writes go to wb (disjoint buffers)

    // epilogue: z = Wh.h + x, h' = sigmoid(z); write into wb (swizzled)
    #pragma unroll
    for (int t = 0; t < 4; ++t) {
      float hv4[4];
      #pragma unroll
      for (int i = 0; i < 4; ++i) {
        float z = acc[t][i] + bf2f((unsigned short)xv[t][i]);
        float e = __expf(-z);
        hv4[i] = __builtin_amdgcn_rcpf(1.f + e);
      }
      int2 hpk;
      hpk.x = pkcvt(hv4[0], hv4[1]);
      hpk.y = pkcvt(hv4[2], hv4[3]);
      if (s == 511) {
        #pragma unroll
        for (int i = 0; i < 4; ++i) {
          int m = m0 + t * 16 + q * 4 + i;
          d_out[64 + (g * 16 + n) * 512 + m] = hv4[i];
        }
      }
      // k = m0 + t*16 + q*4 + i  ->  swizzled addr
      int ktw   = 2 * w + (t >> 1);
      int laneW = ((t & 1) * 2 + (q >> 1)) * 16 + n;
      *(short4_t*)&wb[ktw * 512 + laneW * 8 + (q & 1) * 4] =
          __builtin_bit_cast(short4_t, hpk);
    }

    // prefetch next step's x (consumed regs now free)
    xrow += 64 * 512;
    if (s < 511) {
      #pragma unroll
      for (int t = 0; t < 4; ++t) xv[t] = *(const short4_t*)&xrow[t * 16 + q * 4];
    }

    LDS_BARRIER();   // single barrier: wb complete & visible before next step reads it
  }
}

// ---------- kernel C: sig[b] = sigmoid(hidden[b] . Wf + bf) ----------
__global__ __launch_bounds__(256) void kfin(const float* __restrict__ hid,  // d_out+64, [64][512]
                                            const float* __restrict__ Wf,   // [512]
                                            const float* __restrict__ bfp,  // [1]
                                            float* __restrict__ out) {
  __shared__ float red[4][64];
  int t = threadIdx.x, b = t & 63, qq = t >> 6;
  const float4* hv = (const float4*)&hid[b * 512 + qq * 128];
  const float4* wv = (const float4*)&Wf[qq * 128];
  float p = 0.f;
  #pragma unroll 8
  for (int k = 0; k < 32; ++k) {
    float4 hx = hv[k]; float4 wx = wv[k];
    p += hx.x * wx.x + hx.y * wx.y + hx.z * wx.z + hx.w * wx.w;
  }
  red[qq][b] = p;
  __syncthreads();
  if (t < 64) {
    float z = red[0][t] + red[1][t] + red[2][t] + red[3][t] + bfp[0];
    out[t] = 1.f / (1.f + __expf(-z));
  }
}

extern "C" void kernel_launch(void* const* d_in, const int* in_sizes, int n_in,
                              void* d_out, int out_size, void* d_ws, size_t ws_size,
                              hipStream_t stream) {
  const int*   ids = (const int*)d_in[0];
  const float* emb = (const float*)d_in[1];
  const float* Wh  = (const float*)d_in[2];
  const float* bh  = (const float*)d_in[3];
  const float* Wi  = (const float*)d_in[4];
  const float* bi  = (const float*)d_in[5];
  const float* Wf  = (const float*)d_in[6];
  const float* bf_ = (const float*)d_in[7];
  float* out = (float*)d_out;

  short* xp  = (short*)d_ws;                              // [512][64][512] bf16 = 32 MiB
  short* Whb = (short*)((char*)d_ws + (size_t)33554432);  // [512][512] bf16 = 512 KiB
  short* Wib = (short*)((char*)d_ws + (size_t)34078720);  // [512][256] bf16 = 256 KiB
  (void)in_sizes; (void)n_in; (void)out_size; (void)ws_size;

  kcvt  <<<384, 256, 0, stream>>>(Wh, Wi, Whb, Wib);
  kxproj<<<512, 512, 0, stream>>>(ids, emb, Wib, bi, bh, xp);
  krnn  <<<4, 512, 0, stream>>>(Whb, xp, out);
  kfin  <<<1, 256, 0, stream>>>(out + 64, Wf, bf_, out);
}

// Round 11
// 1141.518 us; speedup vs baseline: 1.8059x; 1.8059x over previous
//
#include <hip/hip_runtime.h>
#include <hip/hip_bf16.h>

// ---------- types ----------
typedef __attribute__((ext_vector_type(8))) short short8;   // 8 bf16 = 4 VGPRs (MFMA A/B frag)
typedef __attribute__((ext_vector_type(4))) short short4_t; // 4 bf16
typedef __attribute__((ext_vector_type(4))) float f32x4;    // MFMA C/D frag

__device__ __forceinline__ short f2bf(float x) {
  unsigned int u = __builtin_bit_cast(unsigned int, x);
  unsigned int r = (u + 0x7fffu + ((u >> 16) & 1u)) >> 16;
  return (short)r;
}
__device__ __forceinline__ float bf2f(unsigned short u) {
  unsigned int i = ((unsigned int)u) << 16;
  return __builtin_bit_cast(float, i);
}

// packed f32x2 -> bf16x2 as an int (hardware cvt if available; safe fallback)
__device__ __forceinline__ int pkcvt(float a, float b) {
#if __has_builtin(__builtin_amdgcn_cvt_pk_bf16_f32)
  typedef __attribute__((ext_vector_type(2))) __bf16 bf16x2_t;
  bf16x2_t r = __builtin_amdgcn_cvt_pk_bf16_f32(a, b);
  return __builtin_bit_cast(int, r);
#else
  unsigned int lo = (unsigned short)f2bf(a);
  unsigned int hi = (unsigned short)f2bf(b);
  return (int)(lo | (hi << 16));
#endif
}

// lgkmcnt-only barrier (no vmcnt drain — global prefetches stay in flight)
#define LDS_BARRIER() asm volatile("s_waitcnt lgkmcnt(0)\n\ts_barrier" ::: "memory")

// ---------- kernel W: convert Wh and Wi fp32 -> bf16 ----------
__global__ __launch_bounds__(256) void kcvt(const float* __restrict__ Wh,
                                            const float* __restrict__ Wi,
                                            short* __restrict__ Whb,
                                            short* __restrict__ Wib) {
  int i = blockIdx.x * 256 + threadIdx.x;   // 0..98303 float4 groups
  const float4* src; short4_t* dst; int j;
  if (i < 65536) { src = (const float4*)Wh; dst = (short4_t*)Whb; j = i; }
  else           { src = (const float4*)Wi; dst = (short4_t*)Wib; j = i - 65536; }
  float4 v = src[j];
  short4_t o;
  o[0] = f2bf(v.x); o[1] = f2bf(v.y); o[2] = f2bf(v.z); o[3] = f2bf(v.w);
  dst[j] = o;
}

// ---------- kernel A (MFMA): xp[s][b][h] = sum_e emb[ids[b][s]][e]*Wi[h][e] + bi[h] + bh[h] ----------
// One block per s. 8 waves; wave w owns h range [64w, 64w+64) (4 N-tiles).
// A = emb rows (bf16, staged in LDS), B = Wib rows (bf16, straight from L2).
__global__ __launch_bounds__(512, 2) void kxproj(const int* __restrict__ ids,    // [B=64][S=512]
                                                 const float* __restrict__ emb,  // [V][256] fp32
                                                 const short* __restrict__ Wib,  // [512][256] bf16
                                                 const float* __restrict__ bi,   // [512]
                                                 const float* __restrict__ bh,   // [512]
                                                 short* __restrict__ xp) {       // [S][64][512] bf16
  const int s = blockIdx.x;
  __shared__ short E[64 * 264];   // [b][e] bf16, row stride 264 shorts (528 B)
  __shared__ float bias[512];
  __shared__ int ids_s[64];
  const int tid = threadIdx.x;    // 0..511
  const int w = tid >> 6, l = tid & 63, n = l & 15, q = l >> 4;

  if (tid < 64) ids_s[tid] = ids[tid * 512 + s];
  if (tid < 256) {
    bias[tid]       = bi[tid]       + bh[tid];
    bias[tid + 256] = bi[tid + 256] + bh[tid + 256];
  }
  __syncthreads();

  // stage emb rows -> bf16 LDS: thread t handles row t>>3, 32-e chunk (t&7)
  {
    const int row = tid >> 3, part = tid & 7;
    const float* src = &emb[(size_t)ids_s[row] * 256 + part * 32];
    short* dst = &E[row * 264 + part * 32];
    #pragma unroll
    for (int j = 0; j < 8; ++j) {
      float4 v = ((const float4*)src)[j];
      int2 pk;
      pk.x = pkcvt(v.x, v.y);
      pk.y = pkcvt(v.z, v.w);
      *(int2*)&dst[j * 4] = pk;
    }
  }
  __syncthreads();

  // GEMM: M=64 (batches), N=64 per wave, K=256
  f32x4 acc[4][4];   // [mt][nt]
  #pragma unroll
  for (int mt = 0; mt < 4; ++mt)
    #pragma unroll
    for (int nt = 0; nt < 4; ++nt) acc[mt][nt] = (f32x4){0.f, 0.f, 0.f, 0.f};

  const short* bbase = &Wib[(size_t)(w * 64 + n) * 256 + q * 8];
  #pragma unroll
  for (int kt = 0; kt < 8; ++kt) {
    short8 afrag[4];
    #pragma unroll
    for (int mt = 0; mt < 4; ++mt)
      afrag[mt] = *(const short8*)&E[(mt * 16 + n) * 264 + kt * 32 + q * 8];
    #pragma unroll
    for (int nt = 0; nt < 4; ++nt) {
      short8 bfrag = *(const short8*)&bbase[nt * 16 * 256 + kt * 32];
      #pragma unroll
      for (int mt = 0; mt < 4; ++mt)
        acc[mt][nt] = __builtin_amdgcn_mfma_f32_16x16x32_bf16(afrag[mt], bfrag, acc[mt][nt], 0, 0, 0);
    }
  }

  // epilogue: + bias, cvt bf16, store
  #pragma unroll
  for (int nt = 0; nt < 4; ++nt) {
    float bv = bias[w * 64 + nt * 16 + n];
    #pragma unroll
    for (int mt = 0; mt < 4; ++mt) {
      #pragma unroll
      for (int i = 0; i < 4; ++i) {
        short sv = f2bf(acc[mt][nt][i] + bv);
        xp[((size_t)s * 64 + mt * 16 + q * 4 + i) * 512 + w * 64 + nt * 16 + n] = sv;
      }
    }
  }
}

// ---------- kernel B: the recurrence. 4 WGs x 16 batches, 8 waves (2/SIMD). ----------
// AGPR budget maxed WITHOUT crossing the 256/wave cap (round-10 lesson):
// tiles 0..2 (192 regs) + tile-3 kt 8..15 (32 regs) + acc (16) = 240 <= 256.
// Tile-3 kt 0..7 stays LDS-resident. h state swizzled fragment-major +
// double-buffered: per-kt B-frag read = one linear conflict-free
// ds_read_b128; ONE lgkm-barrier per step.
// DS/step/wave: 24 b128 reads + 4 b64 writes (round 9: 31 + 4).
__global__ __launch_bounds__(512, 2) void krnn(const short* __restrict__ Whb, // [512][512] bf16
                                               const short* __restrict__ xp,  // [S][64][512] bf16
                                               float* __restrict__ d_out) {
  __shared__ short h_lds[2][16 * 512];      // 2 x 16,384 B (swizzled)
  __shared__ short a_lds[8][8 * 512];       // 8 waves x 8 kt-blocks: 65,536 B (total 98,304)
  const int tid = threadIdx.x;
  const int w   = tid >> 6;       // wave 0..7
  const int l   = tid & 63;
  const int n   = l & 15;         // MFMA col / batch-in-group / A-row-in-tile
  const int q   = l >> 4;         // quad 0..3
  const int g   = blockIdx.x;     // batch group 0..3
  const int m0  = w * 64;

  // zero h buf 0 (read at s=0)
  for (int i = tid; i < 16 * 512 / 2; i += 512) ((int*)h_lds[0])[i] = 0;

  // tile 3 (rows m0+48..m0+63): kt 0..7 -> LDS (swizzled), kt 8..15 -> registers
  const short* a3src = &Whb[(m0 + 48 + n) * 512 + q * 8];
  for (int kt = 0; kt < 8; ++kt)
    *(short8*)&a_lds[w][kt * 512 + l * 8] = *(const short8*)&a3src[kt * 32];
  short8 a3hi[8];
  #pragma unroll
  for (int j = 0; j < 8; ++j) a3hi[j] = *(const short8*)&a3src[(8 + j) * 32];

  // register A-frags, tiles 0..2: A[m = n][k = q*8+j]
  short8 areg[3][16];
  #pragma unroll
  for (int t = 0; t < 3; ++t) {
    const short* base = &Whb[(m0 + t * 16 + n) * 512 + q * 8];
    #pragma unroll
    for (int kt = 0; kt < 16; ++kt) areg[t][kt] = *(const short8*)&base[kt * 32];
  }
  __syncthreads();

  const short* a3l = &a_lds[w][l * 8];

  // x for current step: 4 short4 chunks (t tiles, q offset)
  const short* xrow = &xp[(size_t)(g * 16 + n) * 512 + m0];
  short4_t xv[4];
  #pragma unroll
  for (int t = 0; t < 4; ++t) xv[t] = *(const short4_t*)&xrow[t * 16 + q * 4];

  for (int s = 0; s < 512; ++s) {
    const short* rb = h_lds[s & 1];
    short*       wb = h_lds[1 - (s & 1)];

    f32x4 acc[4];
    #pragma unroll
    for (int t = 0; t < 4; ++t) acc[t] = (f32x4){0.f, 0.f, 0.f, 0.f};

    #pragma unroll
    for (int kt = 0; kt < 16; ++kt) {
      short8 bfrag = *(const short8*)&rb[kt * 512 + l * 8];     // linear, conflict-free
      short8 a3 = (kt < 8) ? *(const short8*)&a3l[kt * 512] : a3hi[kt - 8];
      acc[0] = __builtin_amdgcn_mfma_f32_16x16x32_bf16(areg[0][kt], bfrag, acc[0], 0, 0, 0);
      acc[1] = __builtin_amdgcn_mfma_f32_16x16x32_bf16(areg[1][kt], bfrag, acc[1], 0, 0, 0);
      acc[2] = __builtin_amdgcn_mfma_f32_16x16x32_bf16(areg[2][kt], bfrag, acc[2], 0, 0, 0);
      acc[3] = __builtin_amdgcn_mfma_f32_16x16x32_bf16(a3,          bfrag, acc[3], 0, 0, 0);
    }
    // no barrier here: reads hit rb, writes go to wb (disjoint buffers)

    // epilogue: z = Wh.h + x, h' = sigmoid(z); write into wb (swizzled)
    #pragma unroll
    for (int t = 0; t < 4; ++t) {
      float hv4[4];
      #pragma unroll
      for (int i = 0; i < 4; ++i) {
        float z = acc[t][i] + bf2f((unsigned short)xv[t][i]);
        float e = __expf(-z);
        hv4[i] = __builtin_amdgcn_rcpf(1.f + e);
      }
      int2 hpk;
      hpk.x = pkcvt(hv4[0], hv4[1]);
      hpk.y = pkcvt(hv4[2], hv4[3]);
      if (s == 511) {
        #pragma unroll
        for (int i = 0; i < 4; ++i) {
          int m = m0 + t * 16 + q * 4 + i;
          d_out[64 + (g * 16 + n) * 512 + m] = hv4[i];
        }
      }
      // k = m0 + t*16 + q*4 + i  ->  swizzled addr
      int ktw   = 2 * w + (t >> 1);
      int laneW = ((t & 1) * 2 + (q >> 1)) * 16 + n;
      *(short4_t*)&wb[ktw * 512 + laneW * 8 + (q & 1) * 4] =
          __builtin_bit_cast(short4_t, hpk);
    }

    // prefetch next step's x (consumed regs now free)
    xrow += 64 * 512;
    if (s < 511) {
      #pragma unroll
      for (int t = 0; t < 4; ++t) xv[t] = *(const short4_t*)&xrow[t * 16 + q * 4];
    }

    LDS_BARRIER();   // single barrier: wb complete & visible before next step reads it
  }
}

// ---------- kernel C: sig[b] = sigmoid(hidden[b] . Wf + bf) ----------
__global__ __launch_bounds__(256) void kfin(const float* __restrict__ hid,  // d_out+64, [64][512]
                                            const float* __restrict__ Wf,   // [512]
                                            const float* __restrict__ bfp,  // [1]
                                            float* __restrict__ out) {
  __shared__ float red[4][64];
  int t = threadIdx.x, b = t & 63, qq = t >> 6;
  const float4* hv = (const float4*)&hid[b * 512 + qq * 128];
  const float4* wv = (const float4*)&Wf[qq * 128];
  float p = 0.f;
  #pragma unroll 8
  for (int k = 0; k < 32; ++k) {
    float4 hx = hv[k]; float4 wx = wv[k];
    p += hx.x * wx.x + hx.y * wx.y + hx.z * wx.z + hx.w * wx.w;
  }
  red[qq][b] = p;
  __syncthreads();
  if (t < 64) {
    float z = red[0][t] + red[1][t] + red[2][t] + red[3][t] + bfp[0];
    out[t] = 1.f / (1.f + __expf(-z));
  }
}

extern "C" void kernel_launch(void* const* d_in, const int* in_sizes, int n_in,
                              void* d_out, int out_size, void* d_ws, size_t ws_size,
                              hipStream_t stream) {
  const int*   ids = (const int*)d_in[0];
  const float* emb = (const float*)d_in[1];
  const float* Wh  = (const float*)d_in[2];
  const float* bh  = (const float*)d_in[3];
  const float* Wi  = (const float*)d_in[4];
  const float* bi  = (const float*)d_in[5];
  const float* Wf  = (const float*)d_in[6];
  const float* bf_ = (const float*)d_in[7];
  float* out = (float*)d_out;

  short* xp  = (short*)d_ws;                              // [512][64][512] bf16 = 32 MiB
  short* Whb = (short*)((char*)d_ws + (size_t)33554432);  // [512][512] bf16 = 512 KiB
  short* Wib = (short*)((char*)d_ws + (size_t)34078720);  // [512][256] bf16 = 256 KiB
  (void)in_sizes; (void)n_in; (void)out_size; (void)ws_size;

  kcvt  <<<384, 256, 0, stream>>>(Wh, Wi, Whb, Wib);
  kxproj<<<512, 512, 0, stream>>>(ids, emb, Wib, bi, bh, xp);
  krnn  <<<4, 512, 0, stream>>>(Whb, xp, out);
  kfin  <<<1, 256, 0, stream>>>(out + 64, Wf, bf_, out);
}

// Round 12
// 918.805 us; speedup vs baseline: 2.2436x; 1.2424x over previous
//
#include <hip/hip_runtime.h>
#include <hip/hip_bf16.h>

// ---------- types ----------
typedef __attribute__((ext_vector_type(8))) short short8;   // 8 bf16 = 4 VGPRs (MFMA A/B frag)
typedef __attribute__((ext_vector_type(4))) short short4_t; // 4 bf16
typedef __attribute__((ext_vector_type(4))) float f32x4;    // MFMA C/D frag

__device__ __forceinline__ short f2bf(float x) {
  unsigned int u = __builtin_bit_cast(unsigned int, x);
  unsigned int r = (u + 0x7fffu + ((u >> 16) & 1u)) >> 16;
  return (short)r;
}
__device__ __forceinline__ float bf2f(unsigned short u) {
  unsigned int i = ((unsigned int)u) << 16;
  return __builtin_bit_cast(float, i);
}

// packed f32x2 -> bf16x2 as an int (hardware cvt if available; safe fallback)
__device__ __forceinline__ int pkcvt(float a, float b) {
#if __has_builtin(__builtin_amdgcn_cvt_pk_bf16_f32)
  typedef __attribute__((ext_vector_type(2))) __bf16 bf16x2_t;
  bf16x2_t r = __builtin_amdgcn_cvt_pk_bf16_f32(a, b);
  return __builtin_bit_cast(int, r);
#else
  unsigned int lo = (unsigned short)f2bf(a);
  unsigned int hi = (unsigned short)f2bf(b);
  return (int)(lo | (hi << 16));
#endif
}

// lgkmcnt-only barrier (no vmcnt drain — global prefetches stay in flight)
#define LDS_BARRIER() asm volatile("s_waitcnt lgkmcnt(0)\n\ts_barrier" ::: "memory")

// ---------- kernel W: convert Wh and Wi fp32 -> bf16 ----------
__global__ __launch_bounds__(256) void kcvt(const float* __restrict__ Wh,
                                            const float* __restrict__ Wi,
                                            short* __restrict__ Whb,
                                            short* __restrict__ Wib) {
  int i = blockIdx.x * 256 + threadIdx.x;   // 0..98303 float4 groups
  const float4* src; short4_t* dst; int j;
  if (i < 65536) { src = (const float4*)Wh; dst = (short4_t*)Whb; j = i; }
  else           { src = (const float4*)Wi; dst = (short4_t*)Wib; j = i - 65536; }
  float4 v = src[j];
  short4_t o;
  o[0] = f2bf(v.x); o[1] = f2bf(v.y); o[2] = f2bf(v.z); o[3] = f2bf(v.w);
  dst[j] = o;
}

// ---------- kernel A (MFMA): xp[s][b][h] = sum_e emb[ids[b][s]][e]*Wi[h][e] + bi[h] + bh[h] ----------
// One block per s. 8 waves; wave w owns h range [64w, 64w+64) (4 N-tiles).
// A = emb rows (bf16, staged in LDS), B = Wib rows (bf16, straight from L2).
// Epilogue stages C through LDS for coalesced short8 global stores.
__global__ __launch_bounds__(512, 1) void kxproj(const int* __restrict__ ids,    // [B=64][S=512]
                                                 const float* __restrict__ emb,  // [V][256] fp32
                                                 const short* __restrict__ Wib,  // [512][256] bf16
                                                 const float* __restrict__ bi,   // [512]
                                                 const float* __restrict__ bh,   // [512]
                                                 short* __restrict__ xp) {       // [S][64][512] bf16
  const int s = blockIdx.x;
  __shared__ short E[64 * 264];        // [b][e] bf16, row stride 264 shorts
  __shared__ short stage[512 * 66];    // [h][b] bf16, row stride 66 shorts (67,584 B)
  __shared__ float bias[512];
  __shared__ int ids_s[64];
  const int tid = threadIdx.x;    // 0..511
  const int w = tid >> 6, l = tid & 63, n = l & 15, q = l >> 4;

  if (tid < 64) ids_s[tid] = ids[tid * 512 + s];
  if (tid < 256) {
    bias[tid]       = bi[tid]       + bh[tid];
    bias[tid + 256] = bi[tid + 256] + bh[tid + 256];
  }
  __syncthreads();

  // stage emb rows -> bf16 LDS: thread t handles row t>>3, 32-e chunk (t&7)
  {
    const int row = tid >> 3, part = tid & 7;
    const float* src = &emb[(size_t)ids_s[row] * 256 + part * 32];
    short* dst = &E[row * 264 + part * 32];
    #pragma unroll
    for (int j = 0; j < 8; ++j) {
      float4 v = ((const float4*)src)[j];
      int2 pk;
      pk.x = pkcvt(v.x, v.y);
      pk.y = pkcvt(v.z, v.w);
      *(int2*)&dst[j * 4] = pk;
    }
  }
  __syncthreads();

  // GEMM: M=64 (batches), N=64 per wave, K=256
  f32x4 acc[4][4];   // [mt][nt]
  #pragma unroll
  for (int mt = 0; mt < 4; ++mt)
    #pragma unroll
    for (int nt = 0; nt < 4; ++nt) acc[mt][nt] = (f32x4){0.f, 0.f, 0.f, 0.f};

  const short* bbase = &Wib[(size_t)(w * 64 + n) * 256 + q * 8];
  #pragma unroll
  for (int kt = 0; kt < 8; ++kt) {
    short8 afrag[4];
    #pragma unroll
    for (int mt = 0; mt < 4; ++mt)
      afrag[mt] = *(const short8*)&E[(mt * 16 + n) * 264 + kt * 32 + q * 8];
    #pragma unroll
    for (int nt = 0; nt < 4; ++nt) {
      short8 bfrag = *(const short8*)&bbase[nt * 16 * 256 + kt * 32];
      #pragma unroll
      for (int mt = 0; mt < 4; ++mt)
        acc[mt][nt] = __builtin_amdgcn_mfma_f32_16x16x32_bf16(afrag[mt], bfrag, acc[mt][nt], 0, 0, 0);
    }
  }

  // epilogue: + bias, cvt bf16, stage [h][b] with packed b64 writes
  #pragma unroll
  for (int nt = 0; nt < 4; ++nt) {
    float bv = bias[w * 64 + nt * 16 + n];
    #pragma unroll
    for (int mt = 0; mt < 4; ++mt) {
      int2 hpk;
      hpk.x = pkcvt(acc[mt][nt][0] + bv, acc[mt][nt][1] + bv);
      hpk.y = pkcvt(acc[mt][nt][2] + bv, acc[mt][nt][3] + bv);
      int col  = w * 64 + nt * 16 + n;   // h
      int row0 = mt * 16 + q * 4;        // b
      *(short4_t*)&stage[col * 66 + row0] = __builtin_bit_cast(short4_t, hpk);
    }
  }
  __syncthreads();

  // coalesced write-out: wave `part` covers h in [part*64, +64); lane = b.
  {
    int b = tid & 63, part = tid >> 6;
    short* dst = &xp[((size_t)s * 64 + b) * 512 + part * 64];
    #pragma unroll
    for (int j8 = 0; j8 < 8; ++j8) {
      short8 v;
      #pragma unroll
      for (int e = 0; e < 8; ++e) v[e] = stage[(part * 64 + j8 * 8 + e) * 66 + b];
      *(short8*)&dst[j8 * 8] = v;
    }
  }
}

// ---------- kernel B: the recurrence (round-9 winner, verbatim). ----------
// 4 WGs x 16 batches, 8 waves (2/SIMD). Tiles 0..2 register-resident
// (192 AGPR-frags/wave — the empirical allocator sweet spot; 224+ regresses).
// Tile-3 kt 0..14 LDS-resident (swizzled), kt 15 in one register frag.
// h state swizzled fragment-major + double-buffered: per-kt B-frag read is a
// linear conflict-free ds_read_b128; ONE lgkm-barrier per step.
__global__ __launch_bounds__(512, 2) void krnn(const short* __restrict__ Whb, // [512][512] bf16
                                               const short* __restrict__ xp,  // [S][64][512] bf16
                                               float* __restrict__ d_out) {
  __shared__ short h_lds[2][16 * 512];      // 2 x 16,384 B (swizzled)
  __shared__ short a_lds[8][15 * 512];      // 8 waves x 15 kt-blocks: 122,880 B
  const int tid = threadIdx.x;
  const int w   = tid >> 6;       // wave 0..7
  const int l   = tid & 63;
  const int n   = l & 15;         // MFMA col / batch-in-group / A-row-in-tile
  const int q   = l >> 4;         // quad 0..3
  const int g   = blockIdx.x;     // batch group 0..3
  const int m0  = w * 64;

  // zero h buf 0 (read at s=0)
  for (int i = tid; i < 16 * 512 / 2; i += 512) ((int*)h_lds[0])[i] = 0;

  // preload swizzled LDS A tile (kt 0..14) + keep kt=15 frag in registers
  const short* a3src = &Whb[(m0 + 48 + n) * 512 + q * 8];
  for (int kt = 0; kt < 15; ++kt)
    *(short8*)&a_lds[w][kt * 512 + l * 8] = *(const short8*)&a3src[kt * 32];
  short8 a3_15 = *(const short8*)&a3src[15 * 32];

  // register A-frags, tiles 0..2: A[m = n][k = q*8+j]
  short8 areg[3][16];
  #pragma unroll
  for (int t = 0; t < 3; ++t) {
    const short* base = &Whb[(m0 + t * 16 + n) * 512 + q * 8];
    #pragma unroll
    for (int kt = 0; kt < 16; ++kt) areg[t][kt] = *(const short8*)&base[kt * 32];
  }
  __syncthreads();

  const short* a3l = &a_lds[w][l * 8];

  // x for current step: 4 short4 chunks (t tiles, q offset)
  const short* xrow = &xp[(size_t)(g * 16 + n) * 512 + m0];
  short4_t xv[4];
  #pragma unroll
  for (int t = 0; t < 4; ++t) xv[t] = *(const short4_t*)&xrow[t * 16 + q * 4];

  for (int s = 0; s < 512; ++s) {
    const short* rb = h_lds[s & 1];
    short*       wb = h_lds[1 - (s & 1)];

    f32x4 acc[4];
    #pragma unroll
    for (int t = 0; t < 4; ++t) acc[t] = (f32x4){0.f, 0.f, 0.f, 0.f};

    #pragma unroll
    for (int kt = 0; kt < 16; ++kt) {
      short8 bfrag = *(const short8*)&rb[kt * 512 + l * 8];     // linear, conflict-free
      short8 a3 = (kt < 15) ? *(const short8*)&a3l[kt * 512] : a3_15;
      acc[0] = __builtin_amdgcn_mfma_f32_16x16x32_bf16(areg[0][kt], bfrag, acc[0], 0, 0, 0);
      acc[1] = __builtin_amdgcn_mfma_f32_16x16x32_bf16(areg[1][kt], bfrag, acc[1], 0, 0, 0);
      acc[2] = __builtin_amdgcn_mfma_f32_16x16x32_bf16(areg[2][kt], bfrag, acc[2], 0, 0, 0);
      acc[3] = __builtin_amdgcn_mfma_f32_16x16x32_bf16(a3,          bfrag, acc[3], 0, 0, 0);
    }
    // no barrier here: reads hit rb, writes go to wb (disjoint buffers)

    // epilogue: z = Wh.h + x, h' = sigmoid(z); write into wb (swizzled)
    #pragma unroll
    for (int t = 0; t < 4; ++t) {
      float hv4[4];
      #pragma unroll
      for (int i = 0; i < 4; ++i) {
        float z = acc[t][i] + bf2f((unsigned short)xv[t][i]);
        float e = __expf(-z);
        hv4[i] = __builtin_amdgcn_rcpf(1.f + e);
      }
      int2 hpk;
      hpk.x = pkcvt(hv4[0], hv4[1]);
      hpk.y = pkcvt(hv4[2], hv4[3]);
      if (s == 511) {
        #pragma unroll
        for (int i = 0; i < 4; ++i) {
          int m = m0 + t * 16 + q * 4 + i;
          d_out[64 + (g * 16 + n) * 512 + m] = hv4[i];
        }
      }
      // k = m0 + t*16 + q*4 + i  ->  swizzled addr
      int ktw   = 2 * w + (t >> 1);
      int laneW = ((t & 1) * 2 + (q >> 1)) * 16 + n;
      *(short4_t*)&wb[ktw * 512 + laneW * 8 + (q & 1) * 4] =
          __builtin_bit_cast(short4_t, hpk);
    }

    // prefetch next step's x (consumed regs now free)
    xrow += 64 * 512;
    if (s < 511) {
      #pragma unroll
      for (int t = 0; t < 4; ++t) xv[t] = *(const short4_t*)&xrow[t * 16 + q * 4];
    }

    LDS_BARRIER();   // single barrier: wb complete & visible before next step reads it
  }
}

// ---------- kernel C: sig[b] = sigmoid(hidden[b] . Wf + bf) ----------
__global__ __launch_bounds__(256) void kfin(const float* __restrict__ hid,  // d_out+64, [64][512]
                                            const float* __restrict__ Wf,   // [512]
                                            const float* __restrict__ bfp,  // [1]
                                            float* __restrict__ out) {
  __shared__ float red[4][64];
  int t = threadIdx.x, b = t & 63, qq = t >> 6;
  const float4* hv = (const float4*)&hid[b * 512 + qq * 128];
  const float4* wv = (const float4*)&Wf[qq * 128];
  float p = 0.f;
  #pragma unroll 8
  for (int k = 0; k < 32; ++k) {
    float4 hx = hv[k]; float4 wx = wv[k];
    p += hx.x * wx.x + hx.y * wx.y + hx.z * wx.z + hx.w * wx.w;
  }
  red[qq][b] = p;
  __syncthreads();
  if (t < 64) {
    float z = red[0][t] + red[1][t] + red[2][t] + red[3][t] + bfp[0];
    out[t] = 1.f / (1.f + __expf(-z));
  }
}

extern "C" void kernel_launch(void* const* d_in, const int* in_sizes, int n_in,
                              void* d_out, int out_size, void* d_ws, size_t ws_size,
                              hipStream_t stream) {
  const int*   ids = (const int*)d_in[0];
  const float* emb = (const float*)d_in[1];
  const float* Wh  = (const float*)d_in[2];
  const float* bh  = (const float*)d_in[3];
  const float* Wi  = (const float*)d_in[4];
  const float* bi  = (const float*)d_in[5];
  const float* Wf  = (const float*)d_in[6];
  const float* bf_ = (const float*)d_in[7];
  float* out = (float*)d_out;

  short* xp  = (short*)d_ws;                              // [512][64][512] bf16 = 32 MiB
  short* Whb = (short*)((char*)d_ws + (size_t)33554432);  // [512][512] bf16 = 512 KiB
  short* Wib = (short*)((char*)d_ws + (size_t)34078720);  // [512][256] bf16 = 256 KiB
  (void)in_sizes; (void)n_in; (void)out_size; (void)ws_size;

  kcvt  <<<384, 256, 0, stream>>>(Wh, Wi, Whb, Wib);
  kxproj<<<512, 512, 0, stream>>>(ids, emb, Wib, bi, bh, xp);
  krnn  <<<4, 512, 0, stream>>>(Whb, xp, out);
  kfin  <<<1, 256, 0, stream>>>(out + 64, Wf, bf_, out);
}